// Round 12
// baseline (188.641 us; speedup 1.0000x reference)
//
#include <hip/hip_runtime.h>

#define BATCH   1024
#define GROUPS  512
#define ROW_WORDS 68

typedef float f32x4 __attribute__((ext_vector_type(4)));

// ============================================================================
// DIAGNOSTIC: r5-best kernel x 3 full internal passes in ONE dispatch.
//   pass 0 -> d_out  (output correct)
//   pass 1 -> d_ws   (distinct lines from pass 0: no DCE, no absorption vs out)
//   pass 2 -> d_ws   (same addresses as pass 1: measures L2 write absorption)
// X reloaded per pass (passes 2-3 are L2/L3-warm). Guaranteed > fills in both
// hypothesis branches -> the kernel's counters surface in top-5 for the first
// time. Readout (pre-committed):
//   marginal pass = (bench - 144.3)/2 : ~20-25 => steady at write roofline,
//     single-pass cost is cold/fixed; ~55-65 => steady slow, counters say why.
//   FETCH_SIZE >> 26 MB => X overfetch. WRITE_SIZE 384 vs ~256 MiB => L2
//     absorption of rep-3.
// ============================================================================
__global__ __launch_bounds__(256) void hoact_kernel(
    const float4* __restrict__ X4,   // [B*G]
    const float4* __restrict__ P4,   // [G*256]
    float4*       __restrict__ O4,   // [B*G*16]
    float4*       __restrict__ W4)   // ws mirror (or O4 fallback)
{
    __shared__ float tbl[16 * ROW_WORDS];

    const int xcd   = blockIdx.x & 7;
    const int idx   = blockIdx.x >> 3;
    const int g     = xcd * 64 + (idx & 63);
    const int chunk = idx >> 6;
    const int b0    = chunk * 256;
    const int tid   = threadIdx.x;

    {
        const float4 v = P4[g * 256 + tid];
        const int row = tid >> 4, c4 = tid & 15;
        *(float4*)&tbl[row * ROW_WORDS + c4 * 4] = v;
    }

    const int t       = tid & 7;
    const int bl_base = tid >> 3;

    __syncthreads();

    const f32x4 p0a = *(const f32x4*)&tbl[15 * ROW_WORDS + t * 4];
    const f32x4 p0b = *(const f32x4*)&tbl[15 * ROW_WORDS + (t + 8) * 4];

    for (int rep = 0; rep < 3; ++rep) {
        float4* __restrict__ dst = (rep == 0) ? O4 : W4;

        float4 xv[8];
#pragma unroll
        for (int p = 0; p < 8; ++p)
            xv[p] = X4[(b0 + p * 32 + bl_base) * GROUPS + g];

#pragma unroll
        for (int p = 0; p < 8; ++p) {
            const int b = b0 + p * 32 + bl_base;
            const float4 x = xv[p];

            float v0 = __uint_as_float((__float_as_uint(x.x) & ~3u) | 0u);
            float v1 = __uint_as_float((__float_as_uint(x.y) & ~3u) | 1u);
            float v2 = __uint_as_float((__float_as_uint(x.z) & ~3u) | 2u);
            float v3 = __uint_as_float((__float_as_uint(x.w) & ~3u) | 3u);

#define CSWAP(a, b_)                                 \
            {                                        \
                const float lo = fminf((a), (b_));   \
                const float hi = fmaxf((a), (b_));   \
                (a) = lo; (b_) = hi;                 \
            }
            CSWAP(v0, v1);
            CSWAP(v2, v3);
            CSWAP(v0, v2);
            CSWAP(v1, v3);
            CSWAP(v1, v2);
#undef CSWAP

            const int i1 = __float_as_uint(v1) & 3;
            const int i2 = __float_as_uint(v2) & 3;
            const int i3 = __float_as_uint(v3) & 3;

            const float c0 = v0;
            const float c1 = v1 - v0;
            const float c2 = v2 - v1;
            const float c3 = v3 - v2;

            const int e3 = 1 << i3;
            const int e2 = e3 + (1 << i2);
            const int e1 = e2 + (1 << i1);

            const f32x4 p1a = *(const f32x4*)&tbl[e1 * ROW_WORDS + t * 4];
            const f32x4 p1b = *(const f32x4*)&tbl[e1 * ROW_WORDS + (t + 8) * 4];
            const f32x4 p2a = *(const f32x4*)&tbl[e2 * ROW_WORDS + t * 4];
            const f32x4 p2b = *(const f32x4*)&tbl[e2 * ROW_WORDS + (t + 8) * 4];
            const f32x4 p3a = *(const f32x4*)&tbl[e3 * ROW_WORDS + t * 4];
            const f32x4 p3b = *(const f32x4*)&tbl[e3 * ROW_WORDS + (t + 8) * 4];

            float4 oa, ob;
            oa.x = c0 * p0a.x + c1 * p1a.x + c2 * p2a.x + c3 * p3a.x;
            oa.y = c0 * p0a.y + c1 * p1a.y + c2 * p2a.y + c3 * p3a.y;
            oa.z = c0 * p0a.z + c1 * p1a.z + c2 * p2a.z + c3 * p3a.z;
            oa.w = c0 * p0a.w + c1 * p1a.w + c2 * p2a.w + c3 * p3a.w;
            ob.x = c0 * p0b.x + c1 * p1b.x + c2 * p2b.x + c3 * p3b.x;
            ob.y = c0 * p0b.y + c1 * p1b.y + c2 * p2b.y + c3 * p3b.y;
            ob.z = c0 * p0b.z + c1 * p1b.z + c2 * p2b.z + c3 * p3b.z;
            ob.w = c0 * p0b.w + c1 * p1b.w + c2 * p2b.w + c3 * p3b.w;

            const int o_idx = b * (GROUPS * 16) + g * 16 + t;
            dst[o_idx]     = oa;
            dst[o_idx + 8] = ob;
        }
        // order reps; keep all stores live
        __asm__ volatile("" ::: "memory");
    }
}

extern "C" void kernel_launch(void* const* d_in, const int* in_sizes, int n_in,
                              void* d_out, int out_size, void* d_ws, size_t ws_size,
                              hipStream_t stream) {
    const float4* X4 = (const float4*)d_in[0];   // X: [1024, 512, 4] fp32
    const float4* P4 = (const float4*)d_in[1];   // params: [512, 16, 64] fp32
    float4*       O4 = (float4*)d_out;           // out: [1024, 512, 64] fp32

    // passes 2-3 target the workspace if it can mirror the output layout;
    // fallback to O4 (idempotent, still correct).
    float4* W4 = (ws_size >= (size_t)134217728 && d_ws != nullptr)
                     ? (float4*)d_ws : O4;

    hipLaunchKernelGGL(hoact_kernel, dim3(2048), dim3(256), 0, stream,
                       X4, P4, O4, W4);
}

// Round 13
// 179.456 us; speedup vs baseline: 1.0512x; 1.0512x over previous
//
#include <hip/hip_runtime.h>

#define BATCH   1024
#define GROUPS  512
#define ROW_WORDS 68

// s_memrealtime ticks at ~100 MHz (fixed XTAL, clock-invariant):
// 3500 ticks ~= 35 us spin tail.
#define SPIN_TICKS 3500ULL

typedef float f32x4 __attribute__((ext_vector_type(4)));

// ============================================================================
// DIAGNOSTIC (counter-surfacing): r5-best kernel, byte-identical algorithm +
// a post-store SALU spin tail (~35 us, zero memory traffic, zero VALU).
// Purpose: the real kernel has NEVER appeared in the top-5 (always faster
// than the ~85 us harness fills, table ranks by dur). The tail pushes dur to
// ~96 us so the dispatch finally exposes truthful FETCH_SIZE / WRITE_SIZE /
// SQ_LDS_BANK_CONFLICT / OccupancyPercent (spin adds no traffic; the tail
// window also captures lazy writebacks -> WRITE_SIZE is complete).
// Model being tested (from r10/r12 same-harness differences):
//   kernel(n passes) = ~39 us fixed + ~22 us/pass (22 us = write roofline).
// Forks pre-registered in journal: WRITE>=250MB -> write amplification;
// FETCH>=100MB -> X overfetch; Occupancy<=15% -> residency throttle;
// all clean -> fixed cost is latency/drain, not traffic.
// ============================================================================

static __device__ __forceinline__ unsigned long long rtclock() {
    unsigned long long t;
    asm volatile("s_memrealtime %0\n\ts_waitcnt lgkmcnt(0)"
                 : "=s"(t) :: "memory");
    return t;
}

__global__ __launch_bounds__(256) void hoact_kernel(
    const float4* __restrict__ X4,   // [B*G]
    const float4* __restrict__ P4,   // [G*256]
    float4*       __restrict__ O4)   // [B*G*16]
{
    __shared__ float tbl[16 * ROW_WORDS];

    const int xcd   = blockIdx.x & 7;
    const int idx   = blockIdx.x >> 3;
    const int g     = xcd * 64 + (idx & 63);
    const int chunk = idx >> 6;
    const int b0    = chunk * 256;
    const int tid   = threadIdx.x;

    {
        const float4 v = P4[g * 256 + tid];
        const int row = tid >> 4, c4 = tid & 15;
        *(float4*)&tbl[row * ROW_WORDS + c4 * 4] = v;
    }

    const int t       = tid & 7;
    const int bl_base = tid >> 3;

    float4 xv[8];
#pragma unroll
    for (int p = 0; p < 8; ++p)
        xv[p] = X4[(b0 + p * 32 + bl_base) * GROUPS + g];

    __syncthreads();

    const f32x4 p0a = *(const f32x4*)&tbl[15 * ROW_WORDS + t * 4];
    const f32x4 p0b = *(const f32x4*)&tbl[15 * ROW_WORDS + (t + 8) * 4];

#pragma unroll
    for (int p = 0; p < 8; ++p) {
        const int b = b0 + p * 32 + bl_base;
        const float4 x = xv[p];

        float v0 = __uint_as_float((__float_as_uint(x.x) & ~3u) | 0u);
        float v1 = __uint_as_float((__float_as_uint(x.y) & ~3u) | 1u);
        float v2 = __uint_as_float((__float_as_uint(x.z) & ~3u) | 2u);
        float v3 = __uint_as_float((__float_as_uint(x.w) & ~3u) | 3u);

#define CSWAP(a, b_)                                 \
        {                                            \
            const float lo = fminf((a), (b_));       \
            const float hi = fmaxf((a), (b_));       \
            (a) = lo; (b_) = hi;                     \
        }
        CSWAP(v0, v1);
        CSWAP(v2, v3);
        CSWAP(v0, v2);
        CSWAP(v1, v3);
        CSWAP(v1, v2);
#undef CSWAP

        const int i1 = __float_as_uint(v1) & 3;
        const int i2 = __float_as_uint(v2) & 3;
        const int i3 = __float_as_uint(v3) & 3;

        const float c0 = v0;
        const float c1 = v1 - v0;
        const float c2 = v2 - v1;
        const float c3 = v3 - v2;

        const int e3 = 1 << i3;
        const int e2 = e3 + (1 << i2);
        const int e1 = e2 + (1 << i1);

        const f32x4 p1a = *(const f32x4*)&tbl[e1 * ROW_WORDS + t * 4];
        const f32x4 p1b = *(const f32x4*)&tbl[e1 * ROW_WORDS + (t + 8) * 4];
        const f32x4 p2a = *(const f32x4*)&tbl[e2 * ROW_WORDS + t * 4];
        const f32x4 p2b = *(const f32x4*)&tbl[e2 * ROW_WORDS + (t + 8) * 4];
        const f32x4 p3a = *(const f32x4*)&tbl[e3 * ROW_WORDS + t * 4];
        const f32x4 p3b = *(const f32x4*)&tbl[e3 * ROW_WORDS + (t + 8) * 4];

        float4 oa, ob;
        oa.x = c0 * p0a.x + c1 * p1a.x + c2 * p2a.x + c3 * p3a.x;
        oa.y = c0 * p0a.y + c1 * p1a.y + c2 * p2a.y + c3 * p3a.y;
        oa.z = c0 * p0a.z + c1 * p1a.z + c2 * p2a.z + c3 * p3a.z;
        oa.w = c0 * p0a.w + c1 * p1a.w + c2 * p2a.w + c3 * p3a.w;
        ob.x = c0 * p0b.x + c1 * p1b.x + c2 * p2b.x + c3 * p3b.x;
        ob.y = c0 * p0b.y + c1 * p1b.y + c2 * p2b.y + c3 * p3b.y;
        ob.z = c0 * p0b.z + c1 * p1b.z + c2 * p2b.z + c3 * p3b.z;
        ob.w = c0 * p0b.w + c1 * p1b.w + c2 * p2b.w + c3 * p3b.w;

        const int o_idx = b * (GROUPS * 16) + g * 16 + t;
        O4[o_idx]     = oa;
        O4[o_idx + 8] = ob;
    }

    // ---- counter-surfacing spin tail: SALU only, no memory traffic ----
    {
        const unsigned long long t0 = rtclock();
        while (rtclock() - t0 < SPIN_TICKS)
            __builtin_amdgcn_s_sleep(8);
    }
}

extern "C" void kernel_launch(void* const* d_in, const int* in_sizes, int n_in,
                              void* d_out, int out_size, void* d_ws, size_t ws_size,
                              hipStream_t stream) {
    const float4* X4 = (const float4*)d_in[0];   // X: [1024, 512, 4] fp32
    const float4* P4 = (const float4*)d_in[1];   // params: [512, 16, 64] fp32
    float4*       O4 = (float4*)d_out;           // out: [1024, 512, 64] fp32

    hipLaunchKernelGGL(hoact_kernel, dim3(2048), dim3(256), 0, stream,
                       X4, P4, O4);
}